// Round 4
// baseline (174.861 us; speedup 1.0000x reference)
//
#include <hip/hip_runtime.h>
#include <hip/hip_bf16.h>

typedef unsigned short u16;
typedef unsigned int u32;
typedef __attribute__((ext_vector_type(2))) float f32x2;
typedef __attribute__((ext_vector_type(4))) float f32x4;
typedef __attribute__((ext_vector_type(4))) u16 u16x4;
typedef __attribute__((ext_vector_type(8))) u16 u16x8;
typedef __attribute__((ext_vector_type(8))) __bf16 bf16x8;

#define B_ 32
#define T_ 2048
#define MID_ 1024
#define TOPIC_ 512
#define H_ 256
#define ROWS_ 64
#define NCH_ (T_ / ROWS_)   // 32 chunks per batch

// fp32 -> bf16 RNE
static __device__ __forceinline__ u16 f2bf(float x) {
    u32 u = __float_as_uint(x);
    u = (u + 0x7FFFu + ((u >> 16) & 1u)) >> 16;
    return (u16)u;
}
static __device__ __forceinline__ float bf2f(u32 lo16) {
    return __uint_as_float(lo16 << 16);
}

// ---------------- merged prep ----------------
// blocks 0..255   : Wa row h=blk -> bf16, layout [ks=32][h=256][k=32] (linear)
// blocks 256..287 : enc_out[b][h] = Ua_b[h] + sum_d enc[b][d]*Ua_w[h][d], b=blk-256
// block 288       : vsum = sum_h v_w[h]
__global__ __launch_bounds__(256) void k_prep(const float* __restrict__ enc,
                                              const float* __restrict__ Ua_w,
                                              const float* __restrict__ Ua_b,
                                              const float* __restrict__ Wa,
                                              const float* __restrict__ v_w,
                                              float* __restrict__ enc_out,
                                              u16* __restrict__ wa16s,
                                              float* __restrict__ vsum) {
    __shared__ float es[TOPIC_];
    const int blk = blockIdx.x, tid = threadIdx.x;
    if (blk < 256) {
        const int h = blk, k = tid * 4;
        f32x4 w = *(const f32x4*)(Wa + h * MID_ + k);
        u16x4 h4;
        h4[0] = f2bf(w[0]); h4[1] = f2bf(w[1]); h4[2] = f2bf(w[2]); h4[3] = f2bf(w[3]);
        *(u16x4*)&wa16s[(k >> 5) * (H_ * 32) + h * 32 + (k & 31)] = h4;
    } else if (blk < 288) {
        const int b = blk - 256;
        es[tid]       = enc[b * TOPIC_ + tid];
        es[tid + 256] = enc[b * TOPIC_ + 256 + tid];
        __syncthreads();
        const float* ua = Ua_w + (size_t)tid * TOPIC_;
        float s = Ua_b[tid];
        #pragma unroll 4
        for (int d = 0; d < TOPIC_; d += 4) {
            f32x4 u = *(const f32x4*)(ua + d);
            s += u[0] * es[d] + u[1] * es[d + 1] + u[2] * es[d + 2] + u[3] * es[d + 3];
        }
        enc_out[b * H_ + tid] = s;
    } else {
        if (tid < 64) {
            const int lane = tid;
            float s = v_w[lane] + v_w[lane + 64] + v_w[lane + 128] + v_w[lane + 192];
            #pragma unroll
            for (int m = 32; m; m >>= 1) s += __shfl_xor(s, m, 64);
            if (lane == 0) *vsum = s;
        }
    }
}

// ---------------- fused single-pass kernel ----------------
// grid 1024 = (b:32, chunk:32), 512 threads = 8 waves (wrow=wave&1, wcol=wave>>1).
// A (dec 64x1024) -> bf16 LDS persistent, XOR-swizzled, staged slice-by-slice in the
// K-loop (overlaps HBM with MFMA). B (Wa) global->regs, prefetched 1 step ahead.
// Then chunk softmax + weighted sum from the LDS bf16 tile (single dec pass).
__global__ __launch_bounds__(512, 1) void k_fused(const float* __restrict__ dec,
                                                  const int* __restrict__ masks,
                                                  const float* __restrict__ enc_out,
                                                  const float* __restrict__ v_w,
                                                  const float* __restrict__ vsum_p,
                                                  const u16* __restrict__ wa16s,
                                                  float* __restrict__ po,
                                                  float* __restrict__ pms) {
    __shared__ __attribute__((aligned(16))) u16 As[ROWS_ * MID_];  // 128 KB
    __shared__ float partc[4][ROWS_];
    __shared__ float ev[ROWS_];

    const int tid = threadIdx.x;
    const int lane = tid & 63, wave = tid >> 6;
    const int wrow = wave & 1, wcol = wave >> 1;
    const int rl = lane & 15, kgrp = lane >> 4;
    const int wg = blockIdx.x;
    const int b = wg >> 5, chunk = wg & (NCH_ - 1);

    // enc/v per-lane registers (4 col-subtiles)
    float encr[4], vr[4];
    #pragma unroll
    for (int tc = 0; tc < 4; ++tc) {
        const int h = wcol * 64 + tc * 16 + rl;
        encr[tc] = enc_out[b * H_ + h];
        vr[tc] = v_w[h];
    }

    // A staging: thread -> (row, 4-elem k-chunk); 8 KB (64x32 fp32) per K-step
    const int arow = tid >> 3, koff = (tid & 7) * 4;
    const float* asrc = dec + (size_t)(b * T_ + chunk * ROWS_ + arow) * MID_ + koff;
    const int awbase = arow * MID_;
    const int awkey = (arow & 7) << 3;

    // B: per-lane global src (64 lanes cover 1 KB contiguous per tc)
    const u16* bsrc = wa16s + (wcol * 64 + rl) * 32 + kgrp * 8;

    // A fragment read bases
    const int akey = (rl & 7) << 3;
    int arb[2];
    #pragma unroll
    for (int tr = 0; tr < 2; ++tr) arb[tr] = (wrow * 32 + tr * 16 + rl) * MID_;

    f32x4 acc[2][4];
    const f32x4 z = {0.f, 0.f, 0.f, 0.f};
    #pragma unroll
    for (int i = 0; i < 2; ++i)
        #pragma unroll
        for (int j = 0; j < 4; ++j) acc[i][j] = z;

    // ---- prologue: A(0),A(1)->regs, B(0)->regs, A(0)->LDS ----
    f32x4 a0 = *(const f32x4*)(asrc);
    f32x4 a1 = *(const f32x4*)(asrc + 32);
    bf16x8 bcA[4], bcB[4];
    #pragma unroll
    for (int tc = 0; tc < 4; ++tc) bcA[tc] = *(const bf16x8*)(bsrc + tc * 512);
    {
        u16x4 h4;
        #pragma unroll
        for (int i = 0; i < 4; ++i) h4[i] = f2bf(a0[i]);
        *(u16x4*)&As[awbase + (koff ^ awkey)] = h4;
    }
    __syncthreads();

    #define COMPUTE(KS, BW)                                                       \
        do {                                                                      \
            bf16x8 af[2];                                                         \
            _Pragma("unroll") for (int tr = 0; tr < 2; ++tr)                      \
                af[tr] = *(const bf16x8*)&As[arb[tr] + (((KS)*32 + kgrp*8) ^ akey)]; \
            _Pragma("unroll") for (int tr = 0; tr < 2; ++tr)                      \
                _Pragma("unroll") for (int tc = 0; tc < 4; ++tc)                  \
                    acc[tr][tc] = __builtin_amdgcn_mfma_f32_16x16x32_bf16(        \
                        af[tr], BW[tc], acc[tr][tc], 0, 0, 0);                    \
        } while (0)

    #pragma unroll 1
    for (int ks = 0; ks < 32; ks += 2) {
        // even: compute ks with bcA; stage A(ks+1) from a1; load A(ks+2), B(ks+1)
        if (ks + 2 < 32) a0 = *(const f32x4*)(asrc + (ks + 2) * 32);
        {
            const u16* bp = bsrc + (ks + 1) * (H_ * 32);
            #pragma unroll
            for (int tc = 0; tc < 4; ++tc) bcB[tc] = *(const bf16x8*)(bp + tc * 512);
            u16x4 h4;
            #pragma unroll
            for (int i = 0; i < 4; ++i) h4[i] = f2bf(a1[i]);
            *(u16x4*)&As[awbase + ((((ks + 1) * 32) | koff) ^ awkey)] = h4;
        }
        COMPUTE(ks, bcA);
        __syncthreads();

        // odd: compute ks+1 with bcB; stage A(ks+2) from a0; load A(ks+3), B(ks+2)
        if (ks + 3 < 32) a1 = *(const f32x4*)(asrc + (ks + 3) * 32);
        if (ks + 2 < 32) {
            const u16* bp = bsrc + (ks + 2) * (H_ * 32);
            #pragma unroll
            for (int tc = 0; tc < 4; ++tc) bcA[tc] = *(const bf16x8*)(bp + tc * 512);
            u16x4 h4;
            #pragma unroll
            for (int i = 0; i < 4; ++i) h4[i] = f2bf(a0[i]);
            *(u16x4*)&As[awbase + ((((ks + 2) * 32) | koff) ^ awkey)] = h4;
        }
        COMPUTE(ks + 1, bcB);
        __syncthreads();
    }
    #undef COMPUTE

    // ---- logits: part over this wave's 64 cols ----
    // acc[tr][tc][j] = C[row = wrow*32+tr*16+kgrp*4+j][col = wcol*64+tc*16+rl]
    float part[2][4];
    #pragma unroll
    for (int tr = 0; tr < 2; ++tr)
        #pragma unroll
        for (int j = 0; j < 4; ++j) {
            float p = 0.f;
            #pragma unroll
            for (int tc = 0; tc < 4; ++tc)
                p += vr[tc] * tanhf(encr[tc] + acc[tr][tc][j]);
            part[tr][j] = p;
        }
    #pragma unroll
    for (int m = 1; m < 16; m <<= 1)
        #pragma unroll
        for (int tr = 0; tr < 2; ++tr)
            #pragma unroll
            for (int j = 0; j < 4; ++j)
                part[tr][j] += __shfl_xor(part[tr][j], m, 64);
    if (rl == 0) {
        #pragma unroll
        for (int tr = 0; tr < 2; ++tr)
            #pragma unroll
            for (int j = 0; j < 4; ++j)
                partc[wcol][wrow * 32 + tr * 16 + kgrp * 4 + j] = part[tr][j];
    }
    __syncthreads();

    // ---- chunk softmax (64 rows = 64 lanes of wave 0) ----
    if (wave == 0) {
        const int r = lane;
        float a = partc[0][r] + partc[1][r] + partc[2][r] + partc[3][r];
        const int mk = masks[b * T_ + chunk * ROWS_ + r];
        a = mk ? a : -(*vsum_p);          // tanh(-inf) = -1 -> logit = -sum(v)
        float mx = a;
        #pragma unroll
        for (int m = 1; m < 64; m <<= 1) mx = fmaxf(mx, __shfl_xor(mx, m, 64));
        const float e = expf(a - mx);
        float s = e;
        #pragma unroll
        for (int m = 1; m < 64; m <<= 1) s += __shfl_xor(s, m, 64);
        ev[r] = e;
        if (lane == 0) { pms[wg * 2] = mx; pms[wg * 2 + 1] = s; }
    }
    __syncthreads();

    // ---- partial weighted sum from the bf16 LDS tile ----
    f32x2 o = {0.f, 0.f};
    const int m2 = tid * 2;
    #pragma unroll 8
    for (int t = 0; t < ROWS_; ++t) {
        const u32 h2 = *(const u32*)&As[t * MID_ + (m2 ^ ((t & 7) << 3))];
        const float w = ev[t];
        o[0] += w * bf2f(h2 & 0xFFFFu);
        o[1] += w * bf2f(h2 >> 16);
    }
    *(f32x2*)&po[(size_t)wg * MID_ + m2] = o;
}

// ---------------- combine: out[b][m] = sum_c w_c * o_c[m] ----------------
__global__ __launch_bounds__(256) void k_comb(const float* __restrict__ po,
                                              const float* __restrict__ pms,
                                              float* __restrict__ out) {
    __shared__ float wch[NCH_];
    const int b = blockIdx.x, tid = threadIdx.x;
    if (tid < 64) {
        const int c = tid & 31;
        const float mi = pms[(b * NCH_ + c) * 2];
        const float si = pms[(b * NCH_ + c) * 2 + 1];
        float M = mi;
        #pragma unroll
        for (int m = 1; m < 32; m <<= 1) M = fmaxf(M, __shfl_xor(M, m, 64));
        const float w = expf(mi - M);
        float D = si * w;
        #pragma unroll
        for (int m = 1; m < 32; m <<= 1) D += __shfl_xor(D, m, 64);
        if (tid < 32) wch[c] = w / D;
    }
    __syncthreads();
    #pragma unroll
    for (int i = 0; i < 4; ++i) {
        const int mcol = i * 256 + tid;
        float s = 0.f;
        for (int c = 0; c < NCH_; ++c)
            s += wch[c] * po[((size_t)b * NCH_ + c) * MID_ + mcol];
        out[b * MID_ + mcol] = s;
    }
}

extern "C" void kernel_launch(void* const* d_in, const int* in_sizes, int n_in,
                              void* d_out, int out_size, void* d_ws, size_t ws_size,
                              hipStream_t stream) {
    const float* enc   = (const float*)d_in[0];
    const float* dec   = (const float*)d_in[1];
    const int*   masks = (const int*)d_in[2];
    const float* Ua_w  = (const float*)d_in[3];
    const float* Ua_b  = (const float*)d_in[4];
    const float* Wa_w  = (const float*)d_in[5];
    const float* v_w   = (const float*)d_in[6];
    float* out = (float*)d_out;

    char* ws = (char*)d_ws;
    float* enc_out = (float*)(ws + 0);        // 32 KB
    float* vsum    = (float*)(ws + 32768);    // 4 B (padded)
    u16*   wa16s   = (u16*)(ws + 65536);      // 512 KB
    float* pms     = (float*)(ws + 589824);   // 8 KB (1024 x {max,sum}), padded
    float* po      = (float*)(ws + 606208);   // 4 MB (1024 x 1024 partial sums)

    k_prep<<<dim3(289), dim3(256), 0, stream>>>(enc, Ua_w, Ua_b, Wa_w, v_w,
                                                enc_out, wa16s, vsum);
    k_fused<<<dim3(B_ * NCH_), dim3(512), 0, stream>>>(dec, masks, enc_out, v_w, vsum,
                                                       wa16s, po, pms);
    k_comb<<<dim3(B_), dim3(256), 0, stream>>>(po, pms, out);
}